// Round 3
// baseline (581.220 us; speedup 1.0000x reference)
//
#include <hip/hip_runtime.h>

typedef float v2f __attribute__((ext_vector_type(2)));

#define BB 2048
#define TT 1024
#define CC 9
#define HH 36
#define G3 108   // 3*HH gate rows

// One block (128 threads = 2 waves) per batch element.
// Lane tid < 108 owns gate-row tid (r: 0..35, z: 36..71, n: 72..107) and
// computes s[tid] = bias + w_ih[tid,:]·x_t + w_hh[tid,:]·h_{t-1} as one
// 45-long dot (9 scalar fma on uniform x + 18 packed fma on h pairs).
// Gate pre-activations are scattered to LDS; lanes 0..35 combine them into
// h_t and broadcast back. Weights are pinned in VGPRs via asm so the
// compiler cannot sink the loads into the t-loop (R1 failure mode).
__global__ __launch_bounds__(128, 4) void gru_kernel(
    const float* __restrict__ x,      // (B,T,C)
    const float* __restrict__ w_ih,   // (3H,C)
    const float* __restrict__ w_hh,   // (3H,H)
    const float* __restrict__ b_ih,   // (3H)
    const float* __restrict__ b_hh,   // (3H)
    const float* __restrict__ w_head, // (1,H)
    const float* __restrict__ b_head, // (1)
    float* __restrict__ out)          // (B,1)
{
    const int b   = blockIdx.x;
    const int tid = threadIdx.x;

    __shared__ __align__(16) float hbuf[HH];
    __shared__ float sbuf[4 * HH];    // [0,36): r  [36,72): z  [72,108): n_x  [108,144): n_h

    const bool active = tid < G3;
    const bool ngate  = (tid >= 2 * HH) && active;

    // ---- load per-lane weights (one 45-long row each) ----
    v2f   wh[18];                     // w_hh row as 18 float2 pairs
    float wi9[CC];                    // w_ih row as 9 scalars
    float bx = 0.f, bh = 0.f, whead = 0.f;
#pragma unroll
    for (int k = 0; k < 18; ++k) wh[k] = (v2f){0.f, 0.f};
#pragma unroll
    for (int c = 0; c < CC; ++c) wi9[c] = 0.f;

    if (active) {
        const float* ph = w_hh + (size_t)tid * HH;   // 144 B stride -> 8 B aligned
#pragma unroll
        for (int k = 0; k < 18; ++k) wh[k] = *(const v2f*)(ph + 2 * k);
        const float* pi = w_ih + (size_t)tid * CC;
#pragma unroll
        for (int c = 0; c < CC; ++c) wi9[c] = pi[c];
        if (ngate) { bx = b_ih[tid];             bh = b_hh[tid]; }
        else       { bx = b_ih[tid] + b_hh[tid]; bh = 0.f;       }
    }
    if (tid < HH) whead = w_head[tid];

    // ---- pin weights in VGPRs: values become opaque, loads cannot be sunk ----
#pragma unroll
    for (int k = 0; k < 18; ++k) {
        uint64_t t64 = __builtin_bit_cast(uint64_t, wh[k]);
        asm volatile("" : "+v"(t64));
        wh[k] = __builtin_bit_cast(v2f, t64);
    }
#pragma unroll
    for (int c = 0; c < CC; ++c) asm volatile("" : "+v"(wi9[c]));
    asm volatile("" : "+v"(bx), "+v"(bh));

    // ---- state ----
    v2f h2[18];
#pragma unroll
    for (int k = 0; k < 18; ++k) h2[k] = (v2f){0.f, 0.f};
    float h_own = 0.f;                // lanes < 36: h[tid]

    const float* xp = x + (size_t)b * TT * CC;

    // x_t for t=0, broadcast to SGPRs (uniform across the block).
    float xs[CC];
#pragma unroll
    for (int c = 0; c < CC; ++c)
        xs[c] = __int_as_float(__builtin_amdgcn_readfirstlane(__float_as_int(xp[c])));

    for (int t = 0; t < TT; ++t) {
        // issue next step's x loads now; consume at loop bottom (latency hidden)
        float xnv[CC];
        if (t + 1 < TT) {
            const float* nx = xp + CC;
#pragma unroll
            for (int c = 0; c < CC; ++c) xnv[c] = nx[c];
        } else {
#pragma unroll
            for (int c = 0; c < CC; ++c) xnv[c] = 0.f;
        }

        if (active) {
            float ax = bx;                       // x-part chain (9 scalar fma, sgpr src)
#pragma unroll
            for (int c = 0; c < CC; ++c) ax = fmaf(wi9[c], xs[c], ax);
            v2f ah = (v2f){bh, 0.f};             // h-part chain (18 packed fma)
#pragma unroll
            for (int k = 0; k < 18; ++k) ah = __builtin_elementwise_fma(wh[k], h2[k], ah);
            float sh = ah.x + ah.y;
            if (ngate) {
                sbuf[tid]      = ax;             // n_x  (includes b_ih)
                sbuf[tid + HH] = sh;             // n_h  (includes b_hh)
            } else {
                sbuf[tid] = ax + sh;             // r / z pre-activation
            }
        }
        __syncthreads();

        if (tid < HH) {
            float sr  = sbuf[tid];
            float sz  = sbuf[HH + tid];
            float snx = sbuf[2 * HH + tid];
            float gh  = sbuf[3 * HH + tid];
            float r = __builtin_amdgcn_rcpf(1.f + __expf(-sr));
            float z = __builtin_amdgcn_rcpf(1.f + __expf(-sz));
            float a = snx + r * gh;
            float n = 1.f - 2.f * __builtin_amdgcn_rcpf(__expf(2.f * a) + 1.f);
            h_own = z * (h_own - n) + n;
            hbuf[tid] = h_own;
        }
        __syncthreads();

        // broadcast h_t to every lane's registers (uniform-address b128 reads)
#pragma unroll
        for (int q = 0; q < 9; ++q) {
            float4 tq = *(const float4*)&hbuf[4 * q];
            h2[2 * q]     = (v2f){tq.x, tq.y};
            h2[2 * q + 1] = (v2f){tq.z, tq.w};
        }

        // commit prefetched x into SGPRs
#pragma unroll
        for (int c = 0; c < CC; ++c)
            xs[c] = __int_as_float(__builtin_amdgcn_readfirstlane(__float_as_int(xnv[c])));
        xp += CC;
    }

    // head: out[b] = sum_i h[i] * w_head[i] + b_head   (wave 0 only)
    if (tid < 64) {
        float v = (tid < HH) ? h_own * whead : 0.f;
#pragma unroll
        for (int off = 32; off; off >>= 1) v += __shfl_down(v, off);
        if (tid == 0) out[b] = v + b_head[0];
    }
}

extern "C" void kernel_launch(void* const* d_in, const int* in_sizes, int n_in,
                              void* d_out, int out_size, void* d_ws, size_t ws_size,
                              hipStream_t stream) {
    const float* x      = (const float*)d_in[0];
    const float* w_ih   = (const float*)d_in[1];
    const float* w_hh   = (const float*)d_in[2];
    const float* b_ih   = (const float*)d_in[3];
    const float* b_hh   = (const float*)d_in[4];
    const float* w_head = (const float*)d_in[5];
    const float* b_head = (const float*)d_in[6];
    float* out = (float*)d_out;

    gru_kernel<<<BB, 128, 0, stream>>>(x, w_ih, w_hh, b_ih, b_hh,
                                       w_head, b_head, out);
}

// Round 4
// 440.750 us; speedup vs baseline: 1.3187x; 1.3187x over previous
//
#include <hip/hip_runtime.h>

typedef float v2f __attribute__((ext_vector_type(2)));

#define BB 2048
#define TT 1024
#define CC 9
#define HH 36
#define CSTEPS 64                 // timesteps per x-chunk
#define CF (CSTEPS * CC)          // 576 floats = 2304 B per chunk
#define NCH (TT / CSTEPS)         // 16 chunks

__device__ __forceinline__ void pin2(v2f& v) {
    uint64_t t = __builtin_bit_cast(uint64_t, v);
    asm volatile("" : "+v"(t));
    v = __builtin_bit_cast(v2f, t);
}

// async global->LDS, 4 B per lane (wave writes 256 B: lds_base + lane*4)
__device__ __forceinline__ void gload4(const float* g, float* l) {
    __builtin_amdgcn_global_load_lds(
        (const __attribute__((address_space(1))) unsigned int*)g,
        (__attribute__((address_space(3))) unsigned int*)l,
        4, 0, 0);
}

// One wave per batch element. Lane j < 36 owns hidden j, computes its r/z/n
// dots from pinned VGPR weights. h broadcast via tiny LDS roundtrip (1-wave
// block: no barriers needed, per-wave DS ordering). x staged 64 steps at a
// time into double-buffered LDS via global_load_lds, issued a full chunk
// ahead so HBM latency never touches the recurrence chain.
__global__ __launch_bounds__(64, 2) void gru_kernel(
    const float* __restrict__ x,      // (B,T,C)
    const float* __restrict__ w_ih,   // (3H,C)
    const float* __restrict__ w_hh,   // (3H,H)
    const float* __restrict__ b_ih,   // (3H)
    const float* __restrict__ b_hh,   // (3H)
    const float* __restrict__ w_head, // (1,H)
    const float* __restrict__ b_head, // (1)
    float* __restrict__ out)          // (B,1)
{
    const int b = blockIdx.x;
    const int j = threadIdx.x;

    __shared__ __align__(16) float hbuf[64];        // h broadcast (pad to 64)
    __shared__ __align__(16) float xlds[2][CF];     // x chunk double buffer

    // ---- per-lane weights (lane >= 36 loads row 0; values never escape) ----
    const int jj = (j < HH) ? j : 0;
    v2f wr[18], wz[18], wn[18];
    v2f wri[4], wzi[4], wni[4];
    float wri8, wzi8, wni8, br, bz, bni, bnh;
    {
        const float* pr = w_hh + (size_t)jj * HH;
        const float* pz = w_hh + (size_t)(HH + jj) * HH;
        const float* pn = w_hh + (size_t)(2 * HH + jj) * HH;
#pragma unroll
        for (int k = 0; k < 18; ++k) {
            wr[k] = *(const v2f*)(pr + 2 * k);
            wz[k] = *(const v2f*)(pz + 2 * k);
            wn[k] = *(const v2f*)(pn + 2 * k);
        }
        const float* qr = w_ih + (size_t)jj * CC;
        const float* qz = w_ih + (size_t)(HH + jj) * CC;
        const float* qn = w_ih + (size_t)(2 * HH + jj) * CC;
#pragma unroll
        for (int p = 0; p < 4; ++p) {
            wri[p] = (v2f){qr[2 * p], qr[2 * p + 1]};
            wzi[p] = (v2f){qz[2 * p], qz[2 * p + 1]};
            wni[p] = (v2f){qn[2 * p], qn[2 * p + 1]};
        }
        wri8 = qr[8]; wzi8 = qz[8]; wni8 = qn[8];
        br  = b_ih[jj] + b_hh[jj];
        bz  = b_ih[HH + jj] + b_hh[HH + jj];
        bni = b_ih[2 * HH + jj];
        bnh = b_hh[2 * HH + jj];
    }
    // ---- pin: loads may NOT be sunk into the loop (R1 failure mode) ----
#pragma unroll
    for (int k = 0; k < 18; ++k) { pin2(wr[k]); pin2(wz[k]); pin2(wn[k]); }
#pragma unroll
    for (int p = 0; p < 4; ++p) { pin2(wri[p]); pin2(wzi[p]); pin2(wni[p]); }
    asm volatile("" : "+v"(wri8), "+v"(wzi8), "+v"(wni8));
    asm volatile("" : "+v"(br), "+v"(bz), "+v"(bni), "+v"(bnh));

    const float* xg = x + (size_t)b * (TT * CC);

    // prefetch chunk 0
#pragma unroll
    for (int k = 0; k < 9; ++k) gload4(xg + k * 64 + j, &xlds[0][k * 64]);

    v2f h2[18];
#pragma unroll
    for (int k = 0; k < 18; ++k) h2[k] = (v2f){0.f, 0.f};
    float h_own = 0.f;

    for (int c = 0; c < NCH; ++c) {
        // drain this chunk's loads (issued a full chunk ago -> ~free)
        asm volatile("s_waitcnt vmcnt(0)" ::: "memory");
        __builtin_amdgcn_sched_barrier(0);
        // issue next chunk's loads (in flight across the next 64 steps)
        if (c + 1 < NCH) {
            const float* src = xg + (size_t)(c + 1) * CF;
            float* dst = &xlds[(c + 1) & 1][0];
#pragma unroll
            for (int k = 0; k < 9; ++k) gload4(src + k * 64 + j, dst + k * 64);
        }
        const float* xc = &xlds[c & 1][0];

#pragma unroll 2
        for (int s = 0; s < CSTEPS; ++s) {
            const float* xs = xc + s * CC;
            // x reads issue now; latency hides under the h-dot block
            float xv[CC];
#pragma unroll
            for (int cc = 0; cc < CC; ++cc) xv[cc] = xs[cc];

            v2f ar = (v2f){br, 0.f};
            v2f az = (v2f){bz, 0.f};
            v2f an = (v2f){bni, 0.f};
            v2f ag = (v2f){bnh, 0.f};
#pragma unroll
            for (int k = 0; k < 18; ++k) {
                ar = __builtin_elementwise_fma(wr[k], h2[k], ar);
                az = __builtin_elementwise_fma(wz[k], h2[k], az);
                ag = __builtin_elementwise_fma(wn[k], h2[k], ag);
            }
#pragma unroll
            for (int p = 0; p < 4; ++p) {
                v2f xp2 = (v2f){xv[2 * p], xv[2 * p + 1]};
                ar = __builtin_elementwise_fma(wri[p], xp2, ar);
                az = __builtin_elementwise_fma(wzi[p], xp2, az);
                an = __builtin_elementwise_fma(wni[p], xp2, an);
            }
            float sr = fmaf(wri8, xv[8], ar.x + ar.y);
            float sz = fmaf(wzi8, xv[8], az.x + az.y);
            float sn = fmaf(wni8, xv[8], an.x + an.y);
            float gn = ag.x + ag.y;

            float r = __builtin_amdgcn_rcpf(1.f + __expf(-sr));
            float z = __builtin_amdgcn_rcpf(1.f + __expf(-sz));
            float a = sn + r * gn;
            float n = 1.f - 2.f * __builtin_amdgcn_rcpf(__expf(2.f * a) + 1.f);
            h_own = z * (h_own - n) + n;

            // broadcast h_t (1-wave block: DS pipe is per-wave ordered, no barrier)
            hbuf[j] = h_own;
#pragma unroll
            for (int q = 0; q < 9; ++q) {
                float4 tq = *(const float4*)&hbuf[4 * q];
                h2[2 * q]     = (v2f){tq.x, tq.y};
                h2[2 * q + 1] = (v2f){tq.z, tq.w};
            }
        }
    }

    // head: out[b] = sum_j h[j] * w_head[j] + b_head
    float whead = (j < HH) ? w_head[j] : 0.f;
    float v = (j < HH) ? h_own * whead : 0.f;
#pragma unroll
    for (int off = 32; off; off >>= 1) v += __shfl_down(v, off);
    if (j == 0) out[b] = v + b_head[0];
}

extern "C" void kernel_launch(void* const* d_in, const int* in_sizes, int n_in,
                              void* d_out, int out_size, void* d_ws, size_t ws_size,
                              hipStream_t stream) {
    const float* x      = (const float*)d_in[0];
    const float* w_ih   = (const float*)d_in[1];
    const float* w_hh   = (const float*)d_in[2];
    const float* b_ih   = (const float*)d_in[3];
    const float* b_hh   = (const float*)d_in[4];
    const float* w_head = (const float*)d_in[5];
    const float* b_head = (const float*)d_in[6];
    float* out = (float*)d_out;

    gru_kernel<<<BB, 64, 0, stream>>>(x, w_ih, w_hh, b_ih, b_hh,
                                      w_head, b_head, out);
}